// Round 8
// baseline (150.311 us; speedup 1.0000x reference)
//
#include <hip/hip_runtime.h>

#define BB    32
#define CINc  64
#define HHc   32
#define WWc   32
#define COc   64
#define KSc   7
#define GGc   8
#define PADc  3
#define CPGc  8
#define NPIX  (HHc * WWc)      // 1024
#define TILEH 16
#define HALOH (TILEH + 6)      // 22
#define HALOW (WWc + 6)        // 38
#define NPOS  (HALOH * HALOW)  // 836
#define NVALID (19 * 32)       // 608 valid (non-pad) halo positions
#define NPAD   (NPOS - NVALID) // 228

// LDS: 4 planes of float4 indexed by halo position -> conflict-free b128 taps.
// Staging batches all 64 x-loads (one latency exposure per position) and the
// block index is swizzled so all 16 blocks of a batch image share an XCD L2.
__global__ __launch_bounds__(512) void fused_kernel(
    const float* __restrict__ x,      // [B][64][32][32]
    const float* __restrict__ wq,     // [64][64]
    const float* __restrict__ wk,
    const float* __restrict__ wv,
    const float* __restrict__ rel_h,  // [32][7]
    const float* __restrict__ rel_w,  // [32][7]
    const float* __restrict__ cv,     // [8]
    float* __restrict__ out)          // [B][64][32][32]
{
    __shared__ __attribute__((aligned(16))) float4 kvp[4][NPOS];  // 53.5 KB

    // XCD swizzle: blockIdx ≡ b (mod 8) -> same-b blocks co-locate on one XCD
    const int bi   = blockIdx.x;
    const int t    = bi >> 3;            // 0..63
    const int j    = t & 15;             // 16 blocks per batch image
    const int b    = (t >> 4) * 8 + (bi & 7);
    const int g    = j >> 1;
    const int tile = j & 1;
    const int o0   = g * CPGc;
    const int tid  = threadIdx.x;

    const int y0  = tile * TILEH - PADc;       // first halo row (global y)
    const int yv0 = (tile == 0) ? 0 : y0;      // first VALID global y
    const int r0  = yv0 - y0;                  // halo row of first valid row
    const float* xb = x + (size_t)b * CINc * NPIX;

    // ---------- zero-fill pad positions ----------
    if (tid < NPAD) {
        int r, cc;
        if (tid < 114) {                       // 3 fully-invalid rows
            const int rb = (tile == 0) ? 0 : 19;
            r  = rb + tid / 38;
            cc = tid % 38;
        } else {                               // valid rows, pad cols 0-2 & 35-37
            const int tt = tid - 114;
            const int c6 = tt % 6;
            r  = r0 + tt / 6;
            cc = (c6 < 3) ? c6 : (c6 + 32);
        }
        const int p = r * HALOW + cc;
        const float4 z = {0.f, 0.f, 0.f, 0.f};
        kvp[0][p] = z; kvp[1][p] = z; kvp[2][p] = z; kvp[3][p] = z;
    }

    // ---------- stage k,v for valid positions (batched 64-load pattern) ----------
#pragma unroll 1
    for (int i = tid; i < NVALID; i += 512) {
        const int row = i >> 5;
        const int xx  = i & 31;
        const int y   = yv0 + row;
        const int r   = r0 + row;
        const float* xp = xb + y * WWc + xx;

        float xr[CINc];
#pragma unroll
        for (int c = 0; c < CINc; ++c)
            xr[c] = xp[c * NPIX];

        float ak[CPGc], av[CPGc];
#pragma unroll
        for (int oi = 0; oi < CPGc; ++oi) {
            const float* wkr = wk + (o0 + oi) * CINc;   // uniform -> s_load
            const float* wvr = wv + (o0 + oi) * CINc;
            float sk = 0.f, sv = 0.f;
#pragma unroll
            for (int c = 0; c < CINc; ++c) {
                sk = fmaf(xr[c], wkr[c], sk);
                sv = fmaf(xr[c], wvr[c], sv);
            }
            ak[oi] = sk; av[oi] = sv;
        }

        const int p = r * HALOW + (xx + PADc);
        kvp[0][p] = (float4){ak[0], ak[1], ak[2], ak[3]};
        kvp[1][p] = (float4){ak[4], ak[5], ak[6], ak[7]};
        kvp[2][p] = (float4){av[0], av[1], av[2], av[3]};
        kvp[3][p] = (float4){av[4], av[5], av[6], av[7]};
    }

    // ---------- q for own pixel (batched loads) ----------
    const int w  = tid & 31;
    const int lh = tid >> 5;               // 0..15
    const int h  = tile * TILEH + lh;
    const int poff = h * WWc + w;

    float q[CPGc];
    {
        float xr[CINc];
#pragma unroll
        for (int c = 0; c < CINc; ++c)
            xr[c] = xb[c * NPIX + poff];
#pragma unroll
        for (int oi = 0; oi < CPGc; ++oi) {
            const float* wqr = wq + (o0 + oi) * CINc;   // uniform -> s_load
            float a = 0.f;
#pragma unroll
            for (int c = 0; c < CINc; ++c)
                a = fmaf(xr[c], wqr[c], a);
            q[oi] = a;
        }
    }

    // qrel[t] = sum_oi q[oi] * rel[oi][t]
    const bool use_h = (g < 4);
    const float* relp = use_h ? (rel_h + o0 * KSc) : (rel_w + (o0 - 32) * KSc);
    float qrel[KSc];
#pragma unroll
    for (int tt = 0; tt < KSc; ++tt) {
        float s = 0.f;
#pragma unroll
        for (int oi = 0; oi < CPGc; ++oi)
            s = fmaf(q[oi], relp[oi * KSc + tt], s);
        qrel[tt] = s;
    }

    __syncthreads();

    // ---------- taps: score -> exp -> den & acc, fully fused per tap ----------
    float den = 0.f;
    float acc[CPGc];
#pragma unroll
    for (int oi = 0; oi < CPGc; ++oi) acc[oi] = 0.f;

#pragma unroll
    for (int ki = 0; ki < KSc; ++ki) {
        const int rbase = (lh + ki) * HALOW + w;
#pragma unroll
        for (int kj = 0; kj < KSc; ++kj) {
            const int p = rbase + kj;
            const float4 k0 = kvp[0][p];
            const float4 k1 = kvp[1][p];
            const float4 v0 = kvp[2][p];
            const float4 v1 = kvp[3][p];

            float s = use_h ? qrel[ki] : qrel[kj];
            s = fmaf(q[0], k0.x, s); s = fmaf(q[1], k0.y, s);
            s = fmaf(q[2], k0.z, s); s = fmaf(q[3], k0.w, s);
            s = fmaf(q[4], k1.x, s); s = fmaf(q[5], k1.y, s);
            s = fmaf(q[6], k1.z, s); s = fmaf(q[7], k1.w, s);

            const float e = __expf(s);   // |s| stat-bounded << 88: no-max softmax
            den += e;
            acc[0] = fmaf(e, v0.x, acc[0]); acc[1] = fmaf(e, v0.y, acc[1]);
            acc[2] = fmaf(e, v0.z, acc[2]); acc[3] = fmaf(e, v0.w, acc[3]);
            acc[4] = fmaf(e, v1.x, acc[4]); acc[5] = fmaf(e, v1.y, acc[5]);
            acc[6] = fmaf(e, v1.z, acc[6]); acc[7] = fmaf(e, v1.w, acc[7]);
        }
    }

    // ---------- adaptive mask + write ----------
    const int  r  = min(h, HHc - 1 - h);
    const int  lo = (h <= HHc - 1 - h) ? r : r + 1;
    const int  hi = HHc - 1 - r;
    const bool in_ring = (w >= lo) && (w <= hi);
    const float cvg = cv[g];
    float om = ((float)r - 15.0f + cvg * 16.0f) * (1.0f / 3.0f) + 1.0f;
    om = fminf(fmaxf(om, 0.0f), 1.0f);
    const float maskv = in_ring ? om : 1.0f;
    const float scale = maskv / den;

    float* ob = out + ((size_t)b * COc + o0) * NPIX + poff;
#pragma unroll
    for (int oi = 0; oi < CPGc; ++oi)
        ob[(size_t)oi * NPIX] = acc[oi] * scale;
}

extern "C" void kernel_launch(void* const* d_in, const int* in_sizes, int n_in,
                              void* d_out, int out_size, void* d_ws, size_t ws_size,
                              hipStream_t stream) {
    const float* x     = (const float*)d_in[0];
    const float* wq    = (const float*)d_in[1];
    const float* wk    = (const float*)d_in[2];
    const float* wv    = (const float*)d_in[3];
    const float* rel_h = (const float*)d_in[4];
    const float* rel_w = (const float*)d_in[5];
    const float* cv    = (const float*)d_in[6];
    float* out = (float*)d_out;

    fused_kernel<<<512, 512, 0, stream>>>(x, wq, wk, wv, rel_h, rel_w, cv, out);
}

// Round 9
// 106.316 us; speedup vs baseline: 1.4138x; 1.4138x over previous
//
#include <hip/hip_runtime.h>

#define BB    32
#define CINc  64
#define HHc   32
#define WWc   32
#define COc   64
#define KSc   7
#define GGc   8
#define PADc  3
#define CPGc  8
#define NPIX  (HHc * WWc)      // 1024
#define TILEH 16
#define HALOH (TILEH + 6)      // 22
#define HALOW (WWc + 6)        // 38
#define NPOS  (HALOH * HALOW)  // 836
#define NVALID (19 * 32)       // 608 valid (non-pad) halo positions
#define NPAD   (NPOS - NVALID) // 228

// LDS: 4 planes of float4 indexed by halo position -> conflict-free b128 taps.
// Staging uses chunked xv[8] accumulation (known-good: 56 VGPR, no spills).
// Block-index swizzle co-locates all 16 blocks of a batch image on one XCD
// (verified: FETCH 25 -> 10 MB). __launch_bounds__(512,4): LDS caps us at
// 2 blocks/CU = 4 waves/SIMD, so let the allocator have 128 VGPRs.
__global__ __launch_bounds__(512, 4) void fused_kernel(
    const float* __restrict__ x,      // [B][64][32][32]
    const float* __restrict__ wq,     // [64][64]
    const float* __restrict__ wk,
    const float* __restrict__ wv,
    const float* __restrict__ rel_h,  // [32][7]
    const float* __restrict__ rel_w,  // [32][7]
    const float* __restrict__ cv,     // [8]
    float* __restrict__ out)          // [B][64][32][32]
{
    __shared__ __attribute__((aligned(16))) float4 kvp[4][NPOS];  // 53.5 KB

    // XCD swizzle: blockIdx ≡ b (mod 8) -> same-b blocks co-locate on one XCD
    const int bi   = blockIdx.x;
    const int t    = bi >> 3;            // 0..63
    const int j    = t & 15;             // 16 blocks per batch image
    const int b    = (t >> 4) * 8 + (bi & 7);
    const int g    = j >> 1;
    const int tile = j & 1;
    const int o0   = g * CPGc;
    const int tid  = threadIdx.x;

    const int y0  = tile * TILEH - PADc;       // first halo row (global y)
    const int yv0 = (tile == 0) ? 0 : y0;      // first VALID global y
    const int r0  = yv0 - y0;                  // halo row of first valid row
    const float* xb = x + (size_t)b * CINc * NPIX;

    // ---------- zero-fill pad positions ----------
    if (tid < NPAD) {
        int r, cc;
        if (tid < 114) {                       // 3 fully-invalid rows
            const int rb = (tile == 0) ? 0 : 19;
            r  = rb + tid / 38;
            cc = tid % 38;
        } else {                               // valid rows, pad cols 0-2 & 35-37
            const int tt = tid - 114;
            const int c6 = tt % 6;
            r  = r0 + tt / 6;
            cc = (c6 < 3) ? c6 : (c6 + 32);
        }
        const int p = r * HALOW + cc;
        const float4 z = {0.f, 0.f, 0.f, 0.f};
        kvp[0][p] = z; kvp[1][p] = z; kvp[2][p] = z; kvp[3][p] = z;
    }

    // ---------- stage k,v for valid positions (chunked xv[8]) ----------
#pragma unroll 1
    for (int i = tid; i < NVALID; i += 512) {
        const int row = i >> 5;
        const int xx  = i & 31;
        const int y   = yv0 + row;
        const int r   = r0 + row;
        const float* xp = xb + y * WWc + xx;

        float ak[CPGc], av[CPGc];
#pragma unroll
        for (int oi = 0; oi < CPGc; ++oi) { ak[oi] = 0.f; av[oi] = 0.f; }

        for (int c0 = 0; c0 < CINc; c0 += 8) {
            float xv[8];
#pragma unroll
            for (int jj = 0; jj < 8; ++jj)
                xv[jj] = xp[(c0 + jj) * NPIX];
#pragma unroll
            for (int oi = 0; oi < CPGc; ++oi) {
                const float* wkr = wk + (o0 + oi) * CINc + c0;  // uniform -> s_load
                const float* wvr = wv + (o0 + oi) * CINc + c0;
#pragma unroll
                for (int jj = 0; jj < 8; ++jj) {
                    ak[oi] = fmaf(xv[jj], wkr[jj], ak[oi]);
                    av[oi] = fmaf(xv[jj], wvr[jj], av[oi]);
                }
            }
        }

        const int p = r * HALOW + (xx + PADc);
        kvp[0][p] = (float4){ak[0], ak[1], ak[2], ak[3]};
        kvp[1][p] = (float4){ak[4], ak[5], ak[6], ak[7]};
        kvp[2][p] = (float4){av[0], av[1], av[2], av[3]};
        kvp[3][p] = (float4){av[4], av[5], av[6], av[7]};
    }

    // ---------- q for own pixel (chunked) ----------
    const int w  = tid & 31;
    const int lh = tid >> 5;               // 0..15
    const int h  = tile * TILEH + lh;
    const int poff = h * WWc + w;

    float q[CPGc];
#pragma unroll
    for (int oi = 0; oi < CPGc; ++oi) q[oi] = 0.f;

    for (int c0 = 0; c0 < CINc; c0 += 8) {
        float xv[8];
#pragma unroll
        for (int jj = 0; jj < 8; ++jj)
            xv[jj] = xb[(c0 + jj) * NPIX + poff];
#pragma unroll
        for (int oi = 0; oi < CPGc; ++oi) {
            const float* wqr = wq + (o0 + oi) * CINc + c0;      // uniform -> s_load
#pragma unroll
            for (int jj = 0; jj < 8; ++jj)
                q[oi] = fmaf(xv[jj], wqr[jj], q[oi]);
        }
    }

    // qrel[t] = sum_oi q[oi] * rel[oi][t]
    const bool use_h = (g < 4);
    const float* relp = use_h ? (rel_h + o0 * KSc) : (rel_w + (o0 - 32) * KSc);
    float qrel[KSc];
#pragma unroll
    for (int tt = 0; tt < KSc; ++tt) {
        float s = 0.f;
#pragma unroll
        for (int oi = 0; oi < CPGc; ++oi)
            s = fmaf(q[oi], relp[oi * KSc + tt], s);
        qrel[tt] = s;
    }

    __syncthreads();

    // ---------- taps: score -> exp -> den & acc, fully fused per tap ----------
    float den = 0.f;
    float acc[CPGc];
#pragma unroll
    for (int oi = 0; oi < CPGc; ++oi) acc[oi] = 0.f;

#pragma unroll
    for (int ki = 0; ki < KSc; ++ki) {
        const int rbase = (lh + ki) * HALOW + w;
#pragma unroll
        for (int kj = 0; kj < KSc; ++kj) {
            const int p = rbase + kj;
            const float4 k0 = kvp[0][p];
            const float4 k1 = kvp[1][p];
            const float4 v0 = kvp[2][p];
            const float4 v1 = kvp[3][p];

            float s = use_h ? qrel[ki] : qrel[kj];
            s = fmaf(q[0], k0.x, s); s = fmaf(q[1], k0.y, s);
            s = fmaf(q[2], k0.z, s); s = fmaf(q[3], k0.w, s);
            s = fmaf(q[4], k1.x, s); s = fmaf(q[5], k1.y, s);
            s = fmaf(q[6], k1.z, s); s = fmaf(q[7], k1.w, s);

            const float e = __expf(s);   // |s| stat-bounded << 88: no-max softmax
            den += e;
            acc[0] = fmaf(e, v0.x, acc[0]); acc[1] = fmaf(e, v0.y, acc[1]);
            acc[2] = fmaf(e, v0.z, acc[2]); acc[3] = fmaf(e, v0.w, acc[3]);
            acc[4] = fmaf(e, v1.x, acc[4]); acc[5] = fmaf(e, v1.y, acc[5]);
            acc[6] = fmaf(e, v1.z, acc[6]); acc[7] = fmaf(e, v1.w, acc[7]);
        }
    }

    // ---------- adaptive mask + write ----------
    const int  r  = min(h, HHc - 1 - h);
    const int  lo = (h <= HHc - 1 - h) ? r : r + 1;
    const int  hi = HHc - 1 - r;
    const bool in_ring = (w >= lo) && (w <= hi);
    const float cvg = cv[g];
    float om = ((float)r - 15.0f + cvg * 16.0f) * (1.0f / 3.0f) + 1.0f;
    om = fminf(fmaxf(om, 0.0f), 1.0f);
    const float maskv = in_ring ? om : 1.0f;
    const float scale = maskv / den;

    float* ob = out + ((size_t)b * COc + o0) * NPIX + poff;
#pragma unroll
    for (int oi = 0; oi < CPGc; ++oi)
        ob[(size_t)oi * NPIX] = acc[oi] * scale;
}

extern "C" void kernel_launch(void* const* d_in, const int* in_sizes, int n_in,
                              void* d_out, int out_size, void* d_ws, size_t ws_size,
                              hipStream_t stream) {
    const float* x     = (const float*)d_in[0];
    const float* wq    = (const float*)d_in[1];
    const float* wk    = (const float*)d_in[2];
    const float* wv    = (const float*)d_in[3];
    const float* rel_h = (const float*)d_in[4];
    const float* rel_w = (const float*)d_in[5];
    const float* cv    = (const float*)d_in[6];
    float* out = (float*)d_out;

    fused_kernel<<<512, 512, 0, stream>>>(x, wq, wk, wv, rel_h, rel_w, cv, out);
}